// Round 9
// baseline (253.854 us; speedup 1.0000x reference)
//
#include <hip/hip_runtime.h>
#include <hip/hip_bf16.h>
#include <math.h>

#define B_ 2
#define N_ 2048
#define E_ 1024
#define H_ 8

typedef __attribute__((ext_vector_type(8))) short frag8;       // 8 bf16 (4 VGPRs)
typedef __attribute__((ext_vector_type(4))) float f32x4;
typedef __attribute__((ext_vector_type(16))) float f32x16;
typedef __attribute__((ext_vector_type(8))) unsigned short u16x8;

constexpr float LAM_INIT = 0.7836057665316245f; // 0.8 - 0.6*exp(-0.3*12)
constexpr float LOG2E = 1.4426950408889634f;
constexpr float EXP2_GUARD = -23.083120654f;    // -16 * log2(e)

static __device__ __forceinline__ float fast_exp2(float x) {
#if __has_builtin(__builtin_amdgcn_exp2f)
  return __builtin_amdgcn_exp2f(x);
#else
  return exp2f(x);
#endif
}

static __device__ __forceinline__ ushort f2bf(float f) {
  union { float f; unsigned u; } v; v.f = f;
  unsigned r = (v.u + 0x7FFFu + ((v.u >> 16) & 1u)) >> 16;
  return (ushort)r;
}

static __device__ __forceinline__ unsigned pkbf(float a, float b) {
  __hip_bfloat162 h = __float22bfloat162_rn(make_float2(a, b));
  return *(unsigned*)&h;
}

static __device__ __forceinline__ float bf2f_lo(unsigned u) {
  union { unsigned u; float f; } v; v.u = u << 16; return v.f;
}
static __device__ __forceinline__ float bf2f_hi(unsigned u) {
  union { unsigned u; float f; } v; v.u = u & 0xFFFF0000u; return v.f;
}

static __device__ __forceinline__ void async16(const void* g, void* l) {
  __builtin_amdgcn_global_load_lds((const __attribute__((address_space(1))) void*)g,
                                   (__attribute__((address_space(3))) void*)l, 16, 0, 0);
}

// ---------------- fused prep: cast x -> bf16 | 4x weight transpose+cast | lambda ----------------
__global__ __launch_bounds__(256) void prep_kernel(
    const float* __restrict__ x,
    const float* __restrict__ Wq, const float* __restrict__ Wk,
    const float* __restrict__ Wv, const float* __restrict__ Wo,
    const float* __restrict__ lq1, const float* __restrict__ lk1,
    const float* __restrict__ lq2, const float* __restrict__ lk2,
    ushort* __restrict__ xb, ushort* __restrict__ wqkvt, ushort* __restrict__ wot,
    float* __restrict__ lam_out) {
  __shared__ ushort t[64][72];
  const int bx = blockIdx.x;
  const int tid = threadIdx.x;
  if (bx < 2048) {
    // cast x (8 elems/thread)
    int i = bx * 256 + tid;
    const float4* sp = (const float4*)x + (size_t)i * 2;
    float4 a = sp[0], b = sp[1];
    u16x8 o;
    o[0] = f2bf(a.x); o[1] = f2bf(a.y); o[2] = f2bf(a.z); o[3] = f2bf(a.w);
    o[4] = f2bf(b.x); o[5] = f2bf(b.y); o[6] = f2bf(b.z); o[7] = f2bf(b.w);
    *(u16x8*)(xb + (size_t)i * 8) = o;
  } else if (bx < 3072) {
    int idx = bx - 2048;
    int sel = idx >> 8, rem = idx & 255;
    const float* W = (sel == 0) ? Wq : (sel == 1) ? Wk : (sel == 2) ? Wv : Wo;
    ushort* Wt = (sel < 3) ? (wqkvt + (size_t)sel * 1048576) : wot;
    const int c0 = (rem & 15) * 64, r0 = (rem >> 4) * 64;
    {
      int r = tid >> 2, cc = (tid & 3) * 16;
      const float* sp = W + (size_t)(r0 + r) * 1024 + c0 + cc;
      #pragma unroll
      for (int j = 0; j < 4; j++) {
        float4 a = *(const float4*)(sp + j * 4);
        t[cc + j * 4 + 0][r] = f2bf(a.x);
        t[cc + j * 4 + 1][r] = f2bf(a.y);
        t[cc + j * 4 + 2][r] = f2bf(a.z);
        t[cc + j * 4 + 3][r] = f2bf(a.w);
      }
    }
    __syncthreads();
    int c = tid >> 2, rr = (tid & 3) * 16;
    ushort* dp = Wt + (size_t)(c0 + c) * 1024 + r0 + rr;
    *(u16x8*)dp = *(u16x8*)&t[c][rr];
    *(u16x8*)(dp + 8) = *(u16x8*)&t[c][rr + 8];
  } else {
    if (tid < 64) {
      float t1 = lq1[tid] * lk1[tid];
      float t2 = lq2[tid] * lk2[tid];
      #pragma unroll
      for (int off = 32; off > 0; off >>= 1) {
        t1 += __shfl_down(t1, off);
        t2 += __shfl_down(t2, off);
      }
      if (tid == 0) lam_out[0] = expf(t1) - expf(t2) + LAM_INIT;
    }
  }
}

// ---------------- bf16 MFMA GEMM: C[m][ldc] = sc * A[m][lda] @ Bt[n][1024]^T ----------------
// 128x128 tile, 256 thr (4 waves, 2x2), each wave 64x64 = 4x4 mfma tiles, BK=32.
// qscale applied to output cols n < 1024 only (QK fusion: q-scaling incl. log2e fold).
// Also used with A=Wv^T, Bt=xb to produce V ALREADY TRANSPOSED (vt[channel][seq]) — no vtrans pass.
template <int BF16OUT>
__global__ __launch_bounds__(256) void gemm_bf16(const ushort* __restrict__ A, int lda,
                                                 const ushort* __restrict__ Bt,
                                                 void* __restrict__ Cp, int ldc, float qscale) {
  __shared__ ushort As[4096]; // 128 rows x 32 (k-contig), 8 KB
  __shared__ ushort Bs[4096];
  const int tid = threadIdx.x;
  const int w = tid >> 6, l = tid & 63;
  const int quad = l >> 4, col16 = l & 15;
  const int m0 = blockIdx.y * 128, n0 = blockIdx.x * 128;
  const int wm = (w & 1) * 64, wn = (w >> 1) * 64;
  const int lrow = l >> 2, lcol = (l & 3) * 8;
  const float sc = (n0 < 1024) ? qscale : 1.0f;

  f32x4 acc[4][4];
  #pragma unroll
  for (int mt = 0; mt < 4; mt++)
    #pragma unroll
    for (int nt = 0; nt < 4; nt++) acc[mt][nt] = (f32x4){0.f, 0.f, 0.f, 0.f};

  for (int k0 = 0; k0 < 1024; k0 += 32) {
    __syncthreads();
    #pragma unroll
    for (int i = 0; i < 4; i++) {
      int s = w * 4 + i; // wave-uniform
      if (s < 8) {
        const ushort* gp = A + (size_t)(m0 + s * 16 + lrow) * lda + k0 + lcol;
        async16(gp, (char*)As + s * 1024);
      } else {
        int s2 = s - 8;
        const ushort* gp = Bt + (size_t)(n0 + s2 * 16 + lrow) * 1024 + k0 + lcol;
        async16(gp, (char*)Bs + s2 * 1024);
      }
    }
    __syncthreads();
    frag8 af[4], bfr[4];
    #pragma unroll
    for (int mt = 0; mt < 4; mt++)
      af[mt] = *(const frag8*)((const char*)As + (wm + mt * 16 + col16) * 64 + quad * 16);
    #pragma unroll
    for (int nt = 0; nt < 4; nt++)
      bfr[nt] = *(const frag8*)((const char*)Bs + (wn + nt * 16 + col16) * 64 + quad * 16);
    #pragma unroll
    for (int mt = 0; mt < 4; mt++)
      #pragma unroll
      for (int nt = 0; nt < 4; nt++)
        acc[mt][nt] = __builtin_amdgcn_mfma_f32_16x16x32_bf16(af[mt], bfr[nt], acc[mt][nt], 0, 0, 0);
  }

  #pragma unroll
  for (int mt = 0; mt < 4; mt++)
    #pragma unroll
    for (int r = 0; r < 4; r++) {
      int m = m0 + wm + mt * 16 + quad * 4 + r;
      #pragma unroll
      for (int nt = 0; nt < 4; nt++) {
        int n = n0 + wn + nt * 16 + col16;
        float v = acc[mt][nt][r] * sc;
        if (BF16OUT)
          ((ushort*)Cp)[(size_t)m * ldc + n] = f2bf(v);
        else
          ((float*)Cp)[(size_t)m * ldc + n] = v;
      }
    }
}

// ---------------- MFMA flash attention (S^T trick, exp2-folded softmax, split-K2, KT=64) --------
// grid (N/128, 2H, B*2), 256 thr (4 waves). z = b*2+ks; block covers k in [ks*1024, +1024).
// qk layout: [b*N+n][2048] (q cols 0..1023, k cols 1024..2047).
// vt layout: [h*128 + c][4096] (cols = b*N + n) — produced directly by the V gemm.
// Wave w owns 32 q-cols x ALL 128 channels. S^T = K·Q^T with accumulator INITIALIZED to
// -16*log2e and q pre-scaled by D^-0.5*log2e, so P = exp2(st) directly.
// PV computes O^T = V^T·P^T with B-operand built in regs via paired shfl_xor(32).
// Unnormalized O (bf16) + l partials (f32) per split; combine_ln sums+divides.
// Register notes: (256,3) caps VGPR at ~170. KT must stay 64 — KT=128 (round 7) spilled
// (FETCH/WRITE +75 MB each). Round 4: forcing 4 waves/EU spills too. Keep this shape.
__global__ __launch_bounds__(256, 3) void flash_kernel(const ushort* __restrict__ qk,
                                                       const ushort* __restrict__ vt,
                                                       ushort* __restrict__ opart,
                                                       float* __restrict__ lbuf) {
  const int h2 = blockIdx.y;
  const int b = blockIdx.z >> 1, ks = blockIdx.z & 1;
  const int h = h2 >> 1;
  const int tid = threadIdx.x;
  const int w = tid >> 6;
  const int lane31 = tid & 31, half = (tid & 63) >> 5;
  const int i0 = blockIdx.x * 128 + w * 32; // this wave's 32 q-rows

  __shared__ ushort Klds[64 * 64];  // [krow][d], 128B rows, xor-swizzled 16B granules (8 KB)
  __shared__ ushort Vlds[128 * 64]; // [c][k],    128B rows, xor-swizzled (16 KB)

  // hoisted Q B-frags: qf[chk]; B[k=d][n=q]: n=lane31, d = chk*16 + half*8 + j
  frag8 qf[4];
  #pragma unroll
  for (int chk = 0; chk < 4; chk++) {
    const ushort* qp = qk + (size_t)(b * N_ + i0 + lane31) * 2048 +
                       h2 * 64 + chk * 16 + half * 8;
    qf[chk] = *(const frag8*)qp;
  }

  f32x16 o_[4]; // [cm] : channels cm*32.., cols = wave's 32 q
  #pragma unroll
  for (int cm = 0; cm < 4; cm++)
    #pragma unroll
    for (int i = 0; i < 16; i++) o_[cm][i] = 0.f;
  float la0 = 0.f, la1 = 0.f; // paired l accumulators

  const int kbeg = ks * 1024;
  for (int k0 = kbeg; k0 < kbeg + 1024; k0 += 64) {
    __syncthreads(); // previous iter's Klds/Vlds reads complete
    #pragma unroll
    for (int it = 0; it < 2; it++) { // K tile 64x64 (8KB)
      int j = it * 256 + tid;
      int row = j >> 3, sch = (j & 7) ^ (row & 7);
      const ushort* kg = qk + (size_t)(b * N_ + k0 + row) * 2048 + 1024 + h2 * 64 + sch * 8;
      async16(kg, (char*)Klds + it * 4096 + w * 1024);
    }
    #pragma unroll
    for (int it = 0; it < 4; it++) { // V^T tile 128x64 (16KB)
      int j = it * 256 + tid;
      int row = j >> 3, sch = (j & 7) ^ (row & 7);
      const ushort* vg = vt + (size_t)(h * 128 + row) * 4096 + b * N_ + k0 + sch * 8;
      async16(vg, (char*)Vlds + it * 4096 + w * 1024);
    }
    __syncthreads();

    #pragma unroll
    for (int kh = 0; kh < 2; kh++) {
      // S^T tile: 32 k-rows x 32 q-cols, acc pre-loaded with -16*log2e
      f32x16 st;
      #pragma unroll
      for (int i = 0; i < 16; i++) st[i] = EXP2_GUARD;
      const int r = kh * 32 + lane31;
      #pragma unroll
      for (int chk = 0; chk < 4; chk++) {
        frag8 a = *(const frag8*)((const char*)Klds + r * 128 +
                                  (((chk << 1) | half) ^ (r & 7)) * 16);
        st = __builtin_amdgcn_mfma_f32_32x32x16_bf16(a, qf[chk], st, 0, 0, 0);
      }
      // P = exp2(st) directly; paired l partials
      unsigned pk[8];
      #pragma unroll
      for (int p = 0; p < 8; p++) {
        float e0 = fast_exp2(st[2 * p]);
        float e1 = fast_exp2(st[2 * p + 1]);
        la0 += e0;
        la1 += e1;
        pk[p] = pkbf(e0, e1);
      }
      // PV: build B-frags (P^T) in regs, A = V^T from LDS
      #pragma unroll
      for (int c16 = 0; c16 < 2; c16++) {
        unsigned p0 = pk[c16 * 4 + 0], p1 = pk[c16 * 4 + 1];
        unsigned p2 = pk[c16 * 4 + 2], p3 = pk[c16 * 4 + 3];
        // paired-send: half0 sends p2/p3 (partner needs rows 8-11),
        //              half1 sends p0/p1 (partner needs rows 4-7)
        unsigned m1 = (unsigned)__shfl_xor((int)(half ? p0 : p2), 32);
        unsigned m2 = (unsigned)__shfl_xor((int)(half ? p1 : p3), 32);
        union { unsigned u[4]; frag8 f; } u;
        u.u[0] = half ? m1 : p0;
        u.u[1] = half ? m2 : p1;
        u.u[2] = half ? p2 : m1;
        u.u[3] = half ? p3 : m2;
        frag8 bfr = u.f;
        #pragma unroll
        for (int cm = 0; cm < 4; cm++) {
          int c = cm * 32 + lane31;
          int g = (kh * 4 + c16 * 2 + half) ^ (c & 7);
          frag8 a = *(const frag8*)((const char*)Vlds + c * 128 + g * 16);
          o_[cm] = __builtin_amdgcn_mfma_f32_32x32x16_bf16(a, bfr, o_[cm], 0, 0, 0);
        }
      }
    }
  }

  // l: lane's partial covers half the k-rows; partner holds the rest
  float l_acc = la0 + la1;
  float lt = l_acc + __shfl_xor(l_acc, 32);
  if (half == 0)
    lbuf[(size_t)ks * 65536 + (size_t)(b * 16 + h2) * N_ + i0 + lane31] = lt;

  ushort* obase = opart + (size_t)ks * 8388608; // per-split half (2*MN bf16)
  {
    int q = i0 + lane31;
    ushort* ob = obase + ((size_t)((b * 16 + h2) * N_ + q)) * 128;
    #pragma unroll
    for (int cm = 0; cm < 4; cm++)
      #pragma unroll
      for (int g = 0; g < 4; g++) {
        int c = cm * 32 + g * 8 + half * 4;
        uint2 pv;
        pv.x = pkbf(o_[cm][4 * g + 0], o_[cm][4 * g + 1]);
        pv.y = pkbf(o_[cm][4 * g + 2], o_[cm][4 * g + 3]);
        *(uint2*)(ob + c) = pv;
      }
  }
}

// ---------------- combine (split-K sum + diff) + per-head LayerNorm -> bf16 ----------------
__global__ __launch_bounds__(256) void combine_ln_kernel(
    const ushort* __restrict__ opart, const float* __restrict__ lbuf,
    const float* __restrict__ lam_p,
    const float* __restrict__ ln_g, const float* __restrict__ ln_b,
    ushort* __restrict__ onorm) {
  const float lam = lam_p[0];
  const int wave = threadIdx.x >> 6, lane = threadIdx.x & 63;
  const int row = blockIdx.x * 4 + wave; // 0 .. B*H*N-1
  const int n = row & (N_ - 1);
  const int bh = row >> 11;
  const int h = bh & (H_ - 1);
  const int b = bh >> 3;

  const size_t re = (size_t)(b * 16 + 2 * h) * N_ + n;     // even half-head row
  const size_t ro = (size_t)(b * 16 + 2 * h + 1) * N_ + n; // odd half-head row
  const float rle = 1.0f / (lbuf[re] + lbuf[65536 + re]);
  const float rlo = 1.0f / (lbuf[ro] + lbuf[65536 + ro]);

  const int c = lane * 2;
  unsigned e0 = *(const unsigned*)(opart + re * 128 + c);
  unsigned e1 = *(const unsigned*)(opart + 8388608 + re * 128 + c);
  unsigned q0 = *(const unsigned*)(opart + ro * 128 + c);
  unsigned q1 = *(const unsigned*)(opart + 8388608 + ro * 128 + c);
  float ve0 = (bf2f_lo(e0) + bf2f_lo(e1)) * rle;
  float ve1 = (bf2f_hi(e0) + bf2f_hi(e1)) * rle;
  float vo0 = (bf2f_lo(q0) + bf2f_lo(q1)) * rlo;
  float vo1 = (bf2f_hi(q0) + bf2f_hi(q1)) * rlo;
  float v0 = ve0 - lam * vo0;
  float v1 = ve1 - lam * vo1;
  float sum = v0 + v1, ss = v0 * v0 + v1 * v1;
  #pragma unroll
  for (int off = 1; off < 64; off <<= 1) {
    sum += __shfl_xor(sum, off);
    ss += __shfl_xor(ss, off);
  }
  float mu = sum * (1.0f / 128.0f);
  float var = ss * (1.0f / 128.0f) - mu * mu;
  float r = rsqrtf(var + 1e-5f);
  float o0 = (v0 - mu) * r * ln_g[c] + ln_b[c];
  float o1 = (v1 - mu) * r * ln_g[c + 1] + ln_b[c + 1];
  unsigned pkv = (unsigned)f2bf(o0) | ((unsigned)f2bf(o1) << 16);
  *(unsigned*)(onorm + ((size_t)(b * N_ + n)) * E_ + h * 128 + c) = pkv;
}

// ---------------- launch ----------------
extern "C" void kernel_launch(void* const* d_in, const int* in_sizes, int n_in,
                              void* d_out, int out_size, void* d_ws, size_t ws_size,
                              hipStream_t stream) {
  const float* x    = (const float*)d_in[0];
  const float* Wq   = (const float*)d_in[1];
  const float* Wk   = (const float*)d_in[2];
  const float* Wv   = (const float*)d_in[3];
  const float* Wo   = (const float*)d_in[4];
  const float* lq1  = (const float*)d_in[5];
  const float* lk1  = (const float*)d_in[6];
  const float* lq2  = (const float*)d_in[7];
  const float* lk2  = (const float*)d_in[8];
  const float* ln_g = (const float*)d_in[9];
  const float* ln_b = (const float*)d_in[10];
  float* out = (float*)d_out;

  const size_t MN = (size_t)B_ * N_ * E_; // 4194304
  ushort* xb    = (ushort*)d_ws;          // bf16 x              (8 MB)
  ushort* wqkvt = xb + MN;                // bf16 [Wq;Wk;Wv]^T   (6 MB)
  ushort* wot   = wqkvt + 3 * 1048576;    // bf16 Wo^T           (2 MB)
  ushort* qkb   = wot + 1048576;          // bf16 qk [4096][2048] (16 MB)
  ushort* vtb   = qkb + (size_t)4096 * 2048; // bf16 v^T [1024][4096] (8 MB)
  ushort* op    = vtb + MN;               // bf16 partial O x2 splits (32 MB)
  float*  lbuf  = (float*)(op + 4 * MN);  // l partials x2 (512 KB)
  float*  lam   = lbuf + 2 * 65536;
  ushort* onorm = xb;                     // reuse x buffer after both gemms

  prep_kernel<<<dim3(3073), 256, 0, stream>>>(x, Wq, Wk, Wv, Wo, lq1, lk1, lq2, lk2,
                                              xb, wqkvt, wot, lam);

  // QK projection: [4096][1024] @ [2048][1024]^T -> [4096][2048]; q-scale = D^-0.5 * log2e
  gemm_bf16<1><<<dim3(16, 32), 256, 0, stream>>>(xb, 1024, wqkvt, qkb, 2048,
                                                 0.125f * LOG2E);
  // V projection, TRANSPOSED output: vt[ch][seq] = Wv^T[ch][k] · xb[seq][k]
  gemm_bf16<1><<<dim3(32, 8), 256, 0, stream>>>(wqkvt + 2 * 1048576, 1024, xb, vtb, 4096, 1.0f);

  flash_kernel<<<dim3(N_ / 128, 16, B_ * 2), 256, 0, stream>>>(qkb, vtb, op, lbuf);
  combine_ln_kernel<<<dim3(B_ * H_ * N_ / 4), 256, 0, stream>>>(op, lbuf, lam, ln_g, ln_b, onorm);
  gemm_bf16<0><<<dim3(8, 32), 256, 0, stream>>>(onorm, 1024, wot, out, 1024, 1.0f);
}

// Round 10
// 240.645 us; speedup vs baseline: 1.0549x; 1.0549x over previous
//
#include <hip/hip_runtime.h>
#include <hip/hip_bf16.h>
#include <math.h>

#define B_ 2
#define N_ 2048
#define E_ 1024
#define H_ 8

typedef __attribute__((ext_vector_type(8))) short frag8;       // 8 bf16 (4 VGPRs)
typedef __attribute__((ext_vector_type(4))) float f32x4;
typedef __attribute__((ext_vector_type(16))) float f32x16;
typedef __attribute__((ext_vector_type(8))) unsigned short u16x8;

constexpr float LAM_INIT = 0.7836057665316245f; // 0.8 - 0.6*exp(-0.3*12)
constexpr float LOG2E = 1.4426950408889634f;
constexpr float EXP2_GUARD = -23.083120654f;    // -16 * log2(e)

static __device__ __forceinline__ float fast_exp2(float x) {
#if __has_builtin(__builtin_amdgcn_exp2f)
  return __builtin_amdgcn_exp2f(x);
#else
  return exp2f(x);
#endif
}

static __device__ __forceinline__ ushort f2bf(float f) {
  union { float f; unsigned u; } v; v.f = f;
  unsigned r = (v.u + 0x7FFFu + ((v.u >> 16) & 1u)) >> 16;
  return (ushort)r;
}

static __device__ __forceinline__ unsigned pkbf(float a, float b) {
  __hip_bfloat162 h = __float22bfloat162_rn(make_float2(a, b));
  return *(unsigned*)&h;
}

static __device__ __forceinline__ float bf2f_lo(unsigned u) {
  union { unsigned u; float f; } v; v.u = u << 16; return v.f;
}
static __device__ __forceinline__ float bf2f_hi(unsigned u) {
  union { unsigned u; float f; } v; v.u = u & 0xFFFF0000u; return v.f;
}

static __device__ __forceinline__ void async16(const void* g, void* l) {
  __builtin_amdgcn_global_load_lds((const __attribute__((address_space(1))) void*)g,
                                   (__attribute__((address_space(3))) void*)l, 16, 0, 0);
}

// ---------------- fused prep: cast x -> bf16 | 4x weight transpose+cast | lambda ----------------
__global__ __launch_bounds__(256) void prep_kernel(
    const float* __restrict__ x,
    const float* __restrict__ Wq, const float* __restrict__ Wk,
    const float* __restrict__ Wv, const float* __restrict__ Wo,
    const float* __restrict__ lq1, const float* __restrict__ lk1,
    const float* __restrict__ lq2, const float* __restrict__ lk2,
    ushort* __restrict__ xb, ushort* __restrict__ wqkvt, ushort* __restrict__ wot,
    float* __restrict__ lam_out) {
  __shared__ ushort t[64][72];
  const int bx = blockIdx.x;
  const int tid = threadIdx.x;
  if (bx < 2048) {
    // cast x (8 elems/thread)
    int i = bx * 256 + tid;
    const float4* sp = (const float4*)x + (size_t)i * 2;
    float4 a = sp[0], b = sp[1];
    u16x8 o;
    o[0] = f2bf(a.x); o[1] = f2bf(a.y); o[2] = f2bf(a.z); o[3] = f2bf(a.w);
    o[4] = f2bf(b.x); o[5] = f2bf(b.y); o[6] = f2bf(b.z); o[7] = f2bf(b.w);
    *(u16x8*)(xb + (size_t)i * 8) = o;
  } else if (bx < 3072) {
    int idx = bx - 2048;
    int sel = idx >> 8, rem = idx & 255;
    const float* W = (sel == 0) ? Wq : (sel == 1) ? Wk : (sel == 2) ? Wv : Wo;
    ushort* Wt = (sel < 3) ? (wqkvt + (size_t)sel * 1048576) : wot;
    const int c0 = (rem & 15) * 64, r0 = (rem >> 4) * 64;
    {
      int r = tid >> 2, cc = (tid & 3) * 16;
      const float* sp = W + (size_t)(r0 + r) * 1024 + c0 + cc;
      #pragma unroll
      for (int j = 0; j < 4; j++) {
        float4 a = *(const float4*)(sp + j * 4);
        t[cc + j * 4 + 0][r] = f2bf(a.x);
        t[cc + j * 4 + 1][r] = f2bf(a.y);
        t[cc + j * 4 + 2][r] = f2bf(a.z);
        t[cc + j * 4 + 3][r] = f2bf(a.w);
      }
    }
    __syncthreads();
    int c = tid >> 2, rr = (tid & 3) * 16;
    ushort* dp = Wt + (size_t)(c0 + c) * 1024 + r0 + rr;
    *(u16x8*)dp = *(u16x8*)&t[c][rr];
    *(u16x8*)(dp + 8) = *(u16x8*)&t[c][rr + 8];
  } else {
    if (tid < 64) {
      float t1 = lq1[tid] * lk1[tid];
      float t2 = lq2[tid] * lk2[tid];
      #pragma unroll
      for (int off = 32; off > 0; off >>= 1) {
        t1 += __shfl_down(t1, off);
        t2 += __shfl_down(t2, off);
      }
      if (tid == 0) lam_out[0] = expf(t1) - expf(t2) + LAM_INIT;
    }
  }
}

// ---------------- fused QK + V^T projection GEMM (one 768-block launch, 3 blocks/CU) -----------
// id < 512:  qkb[4096][2048]  = xb @ [Wq;Wk]^T   (q cols scaled by D^-0.5*log2e)
// id >= 512: vtb[1024][4096]  = Wv^T @ xb^T      (V produced already transposed)
// Both share the same K-loop: A, Bt k-contiguous with stride 1024, BK=32, 128x128 tile.
__global__ __launch_bounds__(256) void gemm_qkv(const ushort* __restrict__ xb,
                                                const ushort* __restrict__ wqkvt,
                                                ushort* __restrict__ qkb,
                                                ushort* __restrict__ vtb, float qscale) {
  __shared__ ushort As[4096]; // 128 rows x 32 (k-contig), 8 KB
  __shared__ ushort Bs[4096];
  const int id = blockIdx.x;
  const ushort* A; const ushort* Bt; ushort* C;
  int m0, n0, ldc;
  float sc;
  if (id < 512) {
    m0 = (id >> 4) * 128; n0 = (id & 15) * 128;
    A = xb; Bt = wqkvt; C = qkb; ldc = 2048;
    sc = (n0 < 1024) ? qscale : 1.0f;
  } else {
    int id2 = id - 512;
    m0 = (id2 & 7) * 128; n0 = (id2 >> 3) * 128;
    A = wqkvt + 2 * 1048576; Bt = xb; C = vtb; ldc = 4096;
    sc = 1.0f;
  }
  const int tid = threadIdx.x;
  const int w = tid >> 6, l = tid & 63;
  const int quad = l >> 4, col16 = l & 15;
  const int wm = (w & 1) * 64, wn = (w >> 1) * 64;
  const int lrow = l >> 2, lcol = (l & 3) * 8;

  f32x4 acc[4][4];
  #pragma unroll
  for (int mt = 0; mt < 4; mt++)
    #pragma unroll
    for (int nt = 0; nt < 4; nt++) acc[mt][nt] = (f32x4){0.f, 0.f, 0.f, 0.f};

  for (int k0 = 0; k0 < 1024; k0 += 32) {
    __syncthreads();
    #pragma unroll
    for (int i = 0; i < 4; i++) {
      int s = w * 4 + i; // wave-uniform
      if (s < 8) {
        const ushort* gp = A + (size_t)(m0 + s * 16 + lrow) * 1024 + k0 + lcol;
        async16(gp, (char*)As + s * 1024);
      } else {
        int s2 = s - 8;
        const ushort* gp = Bt + (size_t)(n0 + s2 * 16 + lrow) * 1024 + k0 + lcol;
        async16(gp, (char*)Bs + s2 * 1024);
      }
    }
    __syncthreads();
    frag8 af[4], bfr[4];
    #pragma unroll
    for (int mt = 0; mt < 4; mt++)
      af[mt] = *(const frag8*)((const char*)As + (wm + mt * 16 + col16) * 64 + quad * 16);
    #pragma unroll
    for (int nt = 0; nt < 4; nt++)
      bfr[nt] = *(const frag8*)((const char*)Bs + (wn + nt * 16 + col16) * 64 + quad * 16);
    #pragma unroll
    for (int mt = 0; mt < 4; mt++)
      #pragma unroll
      for (int nt = 0; nt < 4; nt++)
        acc[mt][nt] = __builtin_amdgcn_mfma_f32_16x16x32_bf16(af[mt], bfr[nt], acc[mt][nt], 0, 0, 0);
  }

  #pragma unroll
  for (int mt = 0; mt < 4; mt++)
    #pragma unroll
    for (int r = 0; r < 4; r++) {
      int m = m0 + wm + mt * 16 + quad * 4 + r;
      #pragma unroll
      for (int nt = 0; nt < 4; nt++) {
        int n = n0 + wn + nt * 16 + col16;
        C[(size_t)m * ldc + n] = f2bf(acc[mt][nt][r] * sc);
      }
    }
}

// ---------------- bf16 MFMA GEMM (fp32 out) for the output projection ----------------
__global__ __launch_bounds__(256) void gemm_out(const ushort* __restrict__ A,
                                                const ushort* __restrict__ Bt,
                                                float* __restrict__ Cp) {
  __shared__ ushort As[4096];
  __shared__ ushort Bs[4096];
  const int tid = threadIdx.x;
  const int w = tid >> 6, l = tid & 63;
  const int quad = l >> 4, col16 = l & 15;
  const int m0 = blockIdx.y * 128, n0 = blockIdx.x * 128;
  const int wm = (w & 1) * 64, wn = (w >> 1) * 64;
  const int lrow = l >> 2, lcol = (l & 3) * 8;

  f32x4 acc[4][4];
  #pragma unroll
  for (int mt = 0; mt < 4; mt++)
    #pragma unroll
    for (int nt = 0; nt < 4; nt++) acc[mt][nt] = (f32x4){0.f, 0.f, 0.f, 0.f};

  for (int k0 = 0; k0 < 1024; k0 += 32) {
    __syncthreads();
    #pragma unroll
    for (int i = 0; i < 4; i++) {
      int s = w * 4 + i;
      if (s < 8) {
        const ushort* gp = A + (size_t)(m0 + s * 16 + lrow) * 1024 + k0 + lcol;
        async16(gp, (char*)As + s * 1024);
      } else {
        int s2 = s - 8;
        const ushort* gp = Bt + (size_t)(n0 + s2 * 16 + lrow) * 1024 + k0 + lcol;
        async16(gp, (char*)Bs + s2 * 1024);
      }
    }
    __syncthreads();
    frag8 af[4], bfr[4];
    #pragma unroll
    for (int mt = 0; mt < 4; mt++)
      af[mt] = *(const frag8*)((const char*)As + (wm + mt * 16 + col16) * 64 + quad * 16);
    #pragma unroll
    for (int nt = 0; nt < 4; nt++)
      bfr[nt] = *(const frag8*)((const char*)Bs + (wn + nt * 16 + col16) * 64 + quad * 16);
    #pragma unroll
    for (int mt = 0; mt < 4; mt++)
      #pragma unroll
      for (int nt = 0; nt < 4; nt++)
        acc[mt][nt] = __builtin_amdgcn_mfma_f32_16x16x32_bf16(af[mt], bfr[nt], acc[mt][nt], 0, 0, 0);
  }

  #pragma unroll
  for (int mt = 0; mt < 4; mt++)
    #pragma unroll
    for (int r = 0; r < 4; r++) {
      int m = m0 + wm + mt * 16 + quad * 4 + r;
      #pragma unroll
      for (int nt = 0; nt < 4; nt++) {
        int n = n0 + wn + nt * 16 + col16;
        Cp[(size_t)m * 1024 + n] = acc[mt][nt][r];
      }
    }
}

// ---------------- MFMA flash attention (S^T trick, exp2-folded softmax, split-K2, KT=64) --------
// grid (N/128, 2H, B*2), 256 thr (4 waves). z = b*2+ks; block covers k in [ks*1024, +1024).
// qk layout: [b*N+n][2048] (q cols 0..1023, k cols 1024..2047).
// vt layout: [h*128 + c][4096] (cols = b*N + n) — produced directly by the fused gemm.
// Wave w owns 32 q-cols x ALL 128 channels. S^T = K·Q^T with accumulator INITIALIZED to
// -16*log2e and q pre-scaled by D^-0.5*log2e, so P = exp2(st) directly.
// PV computes O^T = V^T·P^T with B-operand built in regs via paired shfl_xor(32).
// Unnormalized O (bf16) + l partials (f32) per split; combine_ln sums+divides.
// Register notes: (256,3) caps VGPR at ~170. KT must stay 64 — KT=128 (round 7) spilled
// (FETCH/WRITE +75 MB each). Round 4: forcing 4 waves/EU spills too. Keep this shape.
__global__ __launch_bounds__(256, 3) void flash_kernel(const ushort* __restrict__ qk,
                                                       const ushort* __restrict__ vt,
                                                       ushort* __restrict__ opart,
                                                       float* __restrict__ lbuf) {
  const int h2 = blockIdx.y;
  const int b = blockIdx.z >> 1, ks = blockIdx.z & 1;
  const int h = h2 >> 1;
  const int tid = threadIdx.x;
  const int w = tid >> 6;
  const int lane31 = tid & 31, half = (tid & 63) >> 5;
  const int i0 = blockIdx.x * 128 + w * 32; // this wave's 32 q-rows

  __shared__ ushort Klds[64 * 64];  // [krow][d], 128B rows, xor-swizzled 16B granules (8 KB)
  __shared__ ushort Vlds[128 * 64]; // [c][k],    128B rows, xor-swizzled (16 KB)

  // hoisted Q B-frags: qf[chk]; B[k=d][n=q]: n=lane31, d = chk*16 + half*8 + j
  frag8 qf[4];
  #pragma unroll
  for (int chk = 0; chk < 4; chk++) {
    const ushort* qp = qk + (size_t)(b * N_ + i0 + lane31) * 2048 +
                       h2 * 64 + chk * 16 + half * 8;
    qf[chk] = *(const frag8*)qp;
  }

  f32x16 o_[4]; // [cm] : channels cm*32.., cols = wave's 32 q
  #pragma unroll
  for (int cm = 0; cm < 4; cm++)
    #pragma unroll
    for (int i = 0; i < 16; i++) o_[cm][i] = 0.f;
  float la0 = 0.f, la1 = 0.f; // paired l accumulators

  const int kbeg = ks * 1024;
  for (int k0 = kbeg; k0 < kbeg + 1024; k0 += 64) {
    __syncthreads(); // previous iter's Klds/Vlds reads complete
    #pragma unroll
    for (int it = 0; it < 2; it++) { // K tile 64x64 (8KB)
      int j = it * 256 + tid;
      int row = j >> 3, sch = (j & 7) ^ (row & 7);
      const ushort* kg = qk + (size_t)(b * N_ + k0 + row) * 2048 + 1024 + h2 * 64 + sch * 8;
      async16(kg, (char*)Klds + it * 4096 + w * 1024);
    }
    #pragma unroll
    for (int it = 0; it < 4; it++) { // V^T tile 128x64 (16KB)
      int j = it * 256 + tid;
      int row = j >> 3, sch = (j & 7) ^ (row & 7);
      const ushort* vg = vt + (size_t)(h * 128 + row) * 4096 + b * N_ + k0 + sch * 8;
      async16(vg, (char*)Vlds + it * 4096 + w * 1024);
    }
    __syncthreads();

    #pragma unroll
    for (int kh = 0; kh < 2; kh++) {
      // S^T tile: 32 k-rows x 32 q-cols, acc pre-loaded with -16*log2e
      f32x16 st;
      #pragma unroll
      for (int i = 0; i < 16; i++) st[i] = EXP2_GUARD;
      const int r = kh * 32 + lane31;
      #pragma unroll
      for (int chk = 0; chk < 4; chk++) {
        frag8 a = *(const frag8*)((const char*)Klds + r * 128 +
                                  (((chk << 1) | half) ^ (r & 7)) * 16);
        st = __builtin_amdgcn_mfma_f32_32x32x16_bf16(a, qf[chk], st, 0, 0, 0);
      }
      // P = exp2(st) directly; paired l partials
      unsigned pk[8];
      #pragma unroll
      for (int p = 0; p < 8; p++) {
        float e0 = fast_exp2(st[2 * p]);
        float e1 = fast_exp2(st[2 * p + 1]);
        la0 += e0;
        la1 += e1;
        pk[p] = pkbf(e0, e1);
      }
      // PV: build B-frags (P^T) in regs, A = V^T from LDS
      #pragma unroll
      for (int c16 = 0; c16 < 2; c16++) {
        unsigned p0 = pk[c16 * 4 + 0], p1 = pk[c16 * 4 + 1];
        unsigned p2 = pk[c16 * 4 + 2], p3 = pk[c16 * 4 + 3];
        // paired-send: half0 sends p2/p3 (partner needs rows 8-11),
        //              half1 sends p0/p1 (partner needs rows 4-7)
        unsigned m1 = (unsigned)__shfl_xor((int)(half ? p0 : p2), 32);
        unsigned m2 = (unsigned)__shfl_xor((int)(half ? p1 : p3), 32);
        union { unsigned u[4]; frag8 f; } u;
        u.u[0] = half ? m1 : p0;
        u.u[1] = half ? m2 : p1;
        u.u[2] = half ? p2 : m1;
        u.u[3] = half ? p3 : m2;
        frag8 bfr = u.f;
        #pragma unroll
        for (int cm = 0; cm < 4; cm++) {
          int c = cm * 32 + lane31;
          int g = (kh * 4 + c16 * 2 + half) ^ (c & 7);
          frag8 a = *(const frag8*)((const char*)Vlds + c * 128 + g * 16);
          o_[cm] = __builtin_amdgcn_mfma_f32_32x32x16_bf16(a, bfr, o_[cm], 0, 0, 0);
        }
      }
    }
  }

  // l: lane's partial covers half the k-rows; partner holds the rest
  float l_acc = la0 + la1;
  float lt = l_acc + __shfl_xor(l_acc, 32);
  if (half == 0)
    lbuf[(size_t)ks * 65536 + (size_t)(b * 16 + h2) * N_ + i0 + lane31] = lt;

  ushort* obase = opart + (size_t)ks * 8388608; // per-split half (2*MN bf16)
  {
    int q = i0 + lane31;
    ushort* ob = obase + ((size_t)((b * 16 + h2) * N_ + q)) * 128;
    #pragma unroll
    for (int cm = 0; cm < 4; cm++)
      #pragma unroll
      for (int g = 0; g < 4; g++) {
        int c = cm * 32 + g * 8 + half * 4;
        uint2 pv;
        pv.x = pkbf(o_[cm][4 * g + 0], o_[cm][4 * g + 1]);
        pv.y = pkbf(o_[cm][4 * g + 2], o_[cm][4 * g + 3]);
        *(uint2*)(ob + c) = pv;
      }
  }
}

// ---------------- combine (split-K sum + diff) + per-head LayerNorm -> bf16 ----------------
__global__ __launch_bounds__(256) void combine_ln_kernel(
    const ushort* __restrict__ opart, const float* __restrict__ lbuf,
    const float* __restrict__ lam_p,
    const float* __restrict__ ln_g, const float* __restrict__ ln_b,
    ushort* __restrict__ onorm) {
  const float lam = lam_p[0];
  const int wave = threadIdx.x >> 6, lane = threadIdx.x & 63;
  const int row = blockIdx.x * 4 + wave; // 0 .. B*H*N-1
  const int n = row & (N_ - 1);
  const int bh = row >> 11;
  const int h = bh & (H_ - 1);
  const int b = bh >> 3;

  const size_t re = (size_t)(b * 16 + 2 * h) * N_ + n;     // even half-head row
  const size_t ro = (size_t)(b * 16 + 2 * h + 1) * N_ + n; // odd half-head row
  const float rle = 1.0f / (lbuf[re] + lbuf[65536 + re]);
  const float rlo = 1.0f / (lbuf[ro] + lbuf[65536 + ro]);

  const int c = lane * 2;
  unsigned e0 = *(const unsigned*)(opart + re * 128 + c);
  unsigned e1 = *(const unsigned*)(opart + 8388608 + re * 128 + c);
  unsigned q0 = *(const unsigned*)(opart + ro * 128 + c);
  unsigned q1 = *(const unsigned*)(opart + 8388608 + ro * 128 + c);
  float ve0 = (bf2f_lo(e0) + bf2f_lo(e1)) * rle;
  float ve1 = (bf2f_hi(e0) + bf2f_hi(e1)) * rle;
  float vo0 = (bf2f_lo(q0) + bf2f_lo(q1)) * rlo;
  float vo1 = (bf2f_hi(q0) + bf2f_hi(q1)) * rlo;
  float v0 = ve0 - lam * vo0;
  float v1 = ve1 - lam * vo1;
  float sum = v0 + v1, ss = v0 * v0 + v1 * v1;
  #pragma unroll
  for (int off = 1; off < 64; off <<= 1) {
    sum += __shfl_xor(sum, off);
    ss += __shfl_xor(ss, off);
  }
  float mu = sum * (1.0f / 128.0f);
  float var = ss * (1.0f / 128.0f) - mu * mu;
  float r = rsqrtf(var + 1e-5f);
  float o0 = (v0 - mu) * r * ln_g[c] + ln_b[c];
  float o1 = (v1 - mu) * r * ln_g[c + 1] + ln_b[c + 1];
  unsigned pkv = (unsigned)f2bf(o0) | ((unsigned)f2bf(o1) << 16);
  *(unsigned*)(onorm + ((size_t)(b * N_ + n)) * E_ + h * 128 + c) = pkv;
}

// ---------------- launch ----------------
extern "C" void kernel_launch(void* const* d_in, const int* in_sizes, int n_in,
                              void* d_out, int out_size, void* d_ws, size_t ws_size,
                              hipStream_t stream) {
  const float* x    = (const float*)d_in[0];
  const float* Wq   = (const float*)d_in[1];
  const float* Wk   = (const float*)d_in[2];
  const float* Wv   = (const float*)d_in[3];
  const float* Wo   = (const float*)d_in[4];
  const float* lq1  = (const float*)d_in[5];
  const float* lk1  = (const float*)d_in[6];
  const float* lq2  = (const float*)d_in[7];
  const float* lk2  = (const float*)d_in[8];
  const float* ln_g = (const float*)d_in[9];
  const float* ln_b = (const float*)d_in[10];
  float* out = (float*)d_out;

  const size_t MN = (size_t)B_ * N_ * E_; // 4194304
  ushort* xb    = (ushort*)d_ws;          // bf16 x              (8 MB)
  ushort* wqkvt = xb + MN;                // bf16 [Wq;Wk;Wv]^T   (6 MB)
  ushort* wot   = wqkvt + 3 * 1048576;    // bf16 Wo^T           (2 MB)
  ushort* qkb   = wot + 1048576;          // bf16 qk [4096][2048] (16 MB)
  ushort* vtb   = qkb + (size_t)4096 * 2048; // bf16 v^T [1024][4096] (8 MB)
  ushort* op    = vtb + MN;               // bf16 partial O x2 splits (32 MB)
  float*  lbuf  = (float*)(op + 4 * MN);  // l partials x2 (512 KB)
  float*  lam   = lbuf + 2 * 65536;
  ushort* onorm = xb;                     // reuse x buffer after the projection gemm

  prep_kernel<<<dim3(3073), 256, 0, stream>>>(x, Wq, Wk, Wv, Wo, lq1, lk1, lq2, lk2,
                                              xb, wqkvt, wot, lam);

  // fused QK + V^T projection in ONE launch (768 blocks = 3 blocks/CU)
  gemm_qkv<<<dim3(768), 256, 0, stream>>>(xb, wqkvt, qkb, vtb, 0.125f * LOG2E);

  flash_kernel<<<dim3(N_ / 128, 16, B_ * 2), 256, 0, stream>>>(qkb, vtb, op, lbuf);
  combine_ln_kernel<<<dim3(B_ * H_ * N_ / 4), 256, 0, stream>>>(op, lbuf, lam, ln_g, ln_b, onorm);
  gemm_out<<<dim3(8, 32), 256, 0, stream>>>(onorm, wot, out);
}

// Round 11
// 228.275 us; speedup vs baseline: 1.1121x; 1.0542x over previous
//
#include <hip/hip_runtime.h>
#include <hip/hip_bf16.h>
#include <math.h>

#define B_ 2
#define N_ 2048
#define E_ 1024
#define H_ 8

typedef __attribute__((ext_vector_type(8))) short frag8;       // 8 bf16 (4 VGPRs)
typedef __attribute__((ext_vector_type(4))) float f32x4;
typedef __attribute__((ext_vector_type(16))) float f32x16;
typedef __attribute__((ext_vector_type(8))) unsigned short u16x8;

constexpr float LAM_INIT = 0.7836057665316245f; // 0.8 - 0.6*exp(-0.3*12)
constexpr float LOG2E = 1.4426950408889634f;
constexpr float EXP2_GUARD = -23.083120654f;    // -16 * log2(e)

static __device__ __forceinline__ float fast_exp2(float x) {
#if __has_builtin(__builtin_amdgcn_exp2f)
  return __builtin_amdgcn_exp2f(x);
#else
  return exp2f(x);
#endif
}

static __device__ __forceinline__ ushort f2bf(float f) {
  union { float f; unsigned u; } v; v.f = f;
  unsigned r = (v.u + 0x7FFFu + ((v.u >> 16) & 1u)) >> 16;
  return (ushort)r;
}

static __device__ __forceinline__ unsigned pkbf(float a, float b) {
  __hip_bfloat162 h = __float22bfloat162_rn(make_float2(a, b));
  return *(unsigned*)&h;
}

static __device__ __forceinline__ float bf2f_lo(unsigned u) {
  union { unsigned u; float f; } v; v.u = u << 16; return v.f;
}
static __device__ __forceinline__ float bf2f_hi(unsigned u) {
  union { unsigned u; float f; } v; v.u = u & 0xFFFF0000u; return v.f;
}

static __device__ __forceinline__ void async16(const void* g, void* l) {
  __builtin_amdgcn_global_load_lds((const __attribute__((address_space(1))) void*)g,
                                   (__attribute__((address_space(3))) void*)l, 16, 0, 0);
}

// ---------------- fused prep: cast x -> bf16 | 4x weight transpose+cast | lambda ----------------
__global__ __launch_bounds__(256) void prep_kernel(
    const float* __restrict__ x,
    const float* __restrict__ Wq, const float* __restrict__ Wk,
    const float* __restrict__ Wv, const float* __restrict__ Wo,
    const float* __restrict__ lq1, const float* __restrict__ lk1,
    const float* __restrict__ lq2, const float* __restrict__ lk2,
    ushort* __restrict__ xb, ushort* __restrict__ wqkvt, ushort* __restrict__ wot,
    float* __restrict__ lam_out) {
  __shared__ ushort t[64][72];
  const int bx = blockIdx.x;
  const int tid = threadIdx.x;
  if (bx < 2048) {
    // cast x (8 elems/thread)
    int i = bx * 256 + tid;
    const float4* sp = (const float4*)x + (size_t)i * 2;
    float4 a = sp[0], b = sp[1];
    u16x8 o;
    o[0] = f2bf(a.x); o[1] = f2bf(a.y); o[2] = f2bf(a.z); o[3] = f2bf(a.w);
    o[4] = f2bf(b.x); o[5] = f2bf(b.y); o[6] = f2bf(b.z); o[7] = f2bf(b.w);
    *(u16x8*)(xb + (size_t)i * 8) = o;
  } else if (bx < 3072) {
    int idx = bx - 2048;
    int sel = idx >> 8, rem = idx & 255;
    const float* W = (sel == 0) ? Wq : (sel == 1) ? Wk : (sel == 2) ? Wv : Wo;
    ushort* Wt = (sel < 3) ? (wqkvt + (size_t)sel * 1048576) : wot;
    const int c0 = (rem & 15) * 64, r0 = (rem >> 4) * 64;
    {
      int r = tid >> 2, cc = (tid & 3) * 16;
      const float* sp = W + (size_t)(r0 + r) * 1024 + c0 + cc;
      #pragma unroll
      for (int j = 0; j < 4; j++) {
        float4 a = *(const float4*)(sp + j * 4);
        t[cc + j * 4 + 0][r] = f2bf(a.x);
        t[cc + j * 4 + 1][r] = f2bf(a.y);
        t[cc + j * 4 + 2][r] = f2bf(a.z);
        t[cc + j * 4 + 3][r] = f2bf(a.w);
      }
    }
    __syncthreads();
    int c = tid >> 2, rr = (tid & 3) * 16;
    ushort* dp = Wt + (size_t)(c0 + c) * 1024 + r0 + rr;
    *(u16x8*)dp = *(u16x8*)&t[c][rr];
    *(u16x8*)(dp + 8) = *(u16x8*)&t[c][rr + 8];
  } else {
    if (tid < 64) {
      float t1 = lq1[tid] * lk1[tid];
      float t2 = lq2[tid] * lk2[tid];
      #pragma unroll
      for (int off = 32; off > 0; off >>= 1) {
        t1 += __shfl_down(t1, off);
        t2 += __shfl_down(t2, off);
      }
      if (tid == 0) lam_out[0] = expf(t1) - expf(t2) + LAM_INIT;
    }
  }
}

// ---------------- fused QK + V^T projection GEMM (one 768-block launch, 3 blocks/CU) -----------
// id < 512:  qkb[4096][2048]  = xb @ [Wq;Wk]^T   (q cols scaled by D^-0.5*log2e)
// id >= 512: vtb[1024][4096]  = Wv^T @ xb^T      (V produced already transposed)
__global__ __launch_bounds__(256) void gemm_qkv(const ushort* __restrict__ xb,
                                                const ushort* __restrict__ wqkvt,
                                                ushort* __restrict__ qkb,
                                                ushort* __restrict__ vtb, float qscale) {
  __shared__ ushort As[4096]; // 128 rows x 32 (k-contig), 8 KB
  __shared__ ushort Bs[4096];
  const int id = blockIdx.x;
  const ushort* A; const ushort* Bt; ushort* C;
  int m0, n0, ldc;
  float sc;
  if (id < 512) {
    m0 = (id >> 4) * 128; n0 = (id & 15) * 128;
    A = xb; Bt = wqkvt; C = qkb; ldc = 2048;
    sc = (n0 < 1024) ? qscale : 1.0f;
  } else {
    int id2 = id - 512;
    m0 = (id2 & 7) * 128; n0 = (id2 >> 3) * 128;
    A = wqkvt + 2 * 1048576; Bt = xb; C = vtb; ldc = 4096;
    sc = 1.0f;
  }
  const int tid = threadIdx.x;
  const int w = tid >> 6, l = tid & 63;
  const int quad = l >> 4, col16 = l & 15;
  const int wm = (w & 1) * 64, wn = (w >> 1) * 64;
  const int lrow = l >> 2, lcol = (l & 3) * 8;

  f32x4 acc[4][4];
  #pragma unroll
  for (int mt = 0; mt < 4; mt++)
    #pragma unroll
    for (int nt = 0; nt < 4; nt++) acc[mt][nt] = (f32x4){0.f, 0.f, 0.f, 0.f};

  for (int k0 = 0; k0 < 1024; k0 += 32) {
    __syncthreads();
    #pragma unroll
    for (int i = 0; i < 4; i++) {
      int s = w * 4 + i; // wave-uniform
      if (s < 8) {
        const ushort* gp = A + (size_t)(m0 + s * 16 + lrow) * 1024 + k0 + lcol;
        async16(gp, (char*)As + s * 1024);
      } else {
        int s2 = s - 8;
        const ushort* gp = Bt + (size_t)(n0 + s2 * 16 + lrow) * 1024 + k0 + lcol;
        async16(gp, (char*)Bs + s2 * 1024);
      }
    }
    __syncthreads();
    frag8 af[4], bfr[4];
    #pragma unroll
    for (int mt = 0; mt < 4; mt++)
      af[mt] = *(const frag8*)((const char*)As + (wm + mt * 16 + col16) * 64 + quad * 16);
    #pragma unroll
    for (int nt = 0; nt < 4; nt++)
      bfr[nt] = *(const frag8*)((const char*)Bs + (wn + nt * 16 + col16) * 64 + quad * 16);
    #pragma unroll
    for (int mt = 0; mt < 4; mt++)
      #pragma unroll
      for (int nt = 0; nt < 4; nt++)
        acc[mt][nt] = __builtin_amdgcn_mfma_f32_16x16x32_bf16(af[mt], bfr[nt], acc[mt][nt], 0, 0, 0);
  }

  #pragma unroll
  for (int mt = 0; mt < 4; mt++)
    #pragma unroll
    for (int r = 0; r < 4; r++) {
      int m = m0 + wm + mt * 16 + quad * 4 + r;
      #pragma unroll
      for (int nt = 0; nt < 4; nt++) {
        int n = n0 + wn + nt * 16 + col16;
        C[(size_t)m * ldc + n] = f2bf(acc[mt][nt][r] * sc);
      }
    }
}

// ---------------- output projection GEMM, 64x128 tiles (512 blocks = 2/CU) ----------------
__global__ __launch_bounds__(256) void gemm_out(const ushort* __restrict__ A,
                                                const ushort* __restrict__ Bt,
                                                float* __restrict__ Cp) {
  __shared__ ushort As[2048]; // 64 rows x 32, 4 KB
  __shared__ ushort Bs[4096]; // 128 rows x 32, 8 KB
  const int tid = threadIdx.x;
  const int w = tid >> 6, l = tid & 63;
  const int quad = l >> 4, col16 = l & 15;
  const int m0 = blockIdx.y * 64, n0 = blockIdx.x * 128;
  const int wm = (w & 1) * 32, wn = (w >> 1) * 64;
  const int lrow = l >> 2, lcol = (l & 3) * 8;

  f32x4 acc[2][4];
  #pragma unroll
  for (int mt = 0; mt < 2; mt++)
    #pragma unroll
    for (int nt = 0; nt < 4; nt++) acc[mt][nt] = (f32x4){0.f, 0.f, 0.f, 0.f};

  for (int k0 = 0; k0 < 1024; k0 += 32) {
    __syncthreads();
    #pragma unroll
    for (int i = 0; i < 3; i++) {
      int s = w * 3 + i; // 0..11, wave-uniform
      if (s < 4) {
        const ushort* gp = A + (size_t)(m0 + s * 16 + lrow) * 1024 + k0 + lcol;
        async16(gp, (char*)As + s * 1024);
      } else {
        int s2 = s - 4;
        const ushort* gp = Bt + (size_t)(n0 + s2 * 16 + lrow) * 1024 + k0 + lcol;
        async16(gp, (char*)Bs + s2 * 1024);
      }
    }
    __syncthreads();
    frag8 af[2], bfr[4];
    #pragma unroll
    for (int mt = 0; mt < 2; mt++)
      af[mt] = *(const frag8*)((const char*)As + (wm + mt * 16 + col16) * 64 + quad * 16);
    #pragma unroll
    for (int nt = 0; nt < 4; nt++)
      bfr[nt] = *(const frag8*)((const char*)Bs + (wn + nt * 16 + col16) * 64 + quad * 16);
    #pragma unroll
    for (int mt = 0; mt < 2; mt++)
      #pragma unroll
      for (int nt = 0; nt < 4; nt++)
        acc[mt][nt] = __builtin_amdgcn_mfma_f32_16x16x32_bf16(af[mt], bfr[nt], acc[mt][nt], 0, 0, 0);
  }

  #pragma unroll
  for (int mt = 0; mt < 2; mt++)
    #pragma unroll
    for (int r = 0; r < 4; r++) {
      int m = m0 + wm + mt * 16 + quad * 4 + r;
      #pragma unroll
      for (int nt = 0; nt < 4; nt++) {
        int n = n0 + wn + nt * 16 + col16;
        Cp[(size_t)m * 1024 + n] = acc[mt][nt][r];
      }
    }
}

// ---------------- MFMA flash attention (S^T, exp2 softmax, split-K2, KT=64, LDS dbuf) ----------
// grid (N/128, 2H, B*2), 256 thr (4 waves). z = b*2+ks; block covers k in [ks*1024, +1024).
// SINGLE-BARRIER double-buffered pipeline: per phase, __syncthreads() (drains loads that had a
// full compute phase to land), THEN issue next tile's async16 into the other static buffer,
// then compute — the barrier never drains a just-issued prefetch (the m97 stall).
// Wave w owns 32 q-cols x ALL 128 channels. S^T = K·Q^T with acc init -16*log2e and q pre-scaled
// by D^-0.5*log2e, so P = exp2(st). PV: O^T = V^T·P^T, B-operand built via paired shfl_xor(32).
// Unnormalized O (bf16) + l partials (f32) per split; combine_ln sums+divides.
// Register notes: do NOT raise min-waves (round-4 spill) and do NOT unroll more k-tiles into the
// body (round-7 spill, FETCH/WRITE +75 MB signature). Spill watch on this dbuf version: FETCH.
__global__ __launch_bounds__(256, 2) void flash_kernel(const ushort* __restrict__ qk,
                                                       const ushort* __restrict__ vt,
                                                       ushort* __restrict__ opart,
                                                       float* __restrict__ lbuf) {
  const int h2 = blockIdx.y;
  const int b = blockIdx.z >> 1, ks = blockIdx.z & 1;
  const int h = h2 >> 1;
  const int tid = threadIdx.x;
  const int w = tid >> 6;
  const int lane31 = tid & 31, half = (tid & 63) >> 5;
  const int i0 = blockIdx.x * 128 + w * 32; // this wave's 32 q-rows

  __shared__ ushort Klds0[64 * 64], Klds1[64 * 64];   // [krow][d], xor-swizzled (8 KB each)
  __shared__ ushort Vlds0[128 * 64], Vlds1[128 * 64]; // [c][k],    xor-swizzled (16 KB each)

  // hoisted Q B-frags
  frag8 qf[4];
  #pragma unroll
  for (int chk = 0; chk < 4; chk++) {
    const ushort* qp = qk + (size_t)(b * N_ + i0 + lane31) * 2048 +
                       h2 * 64 + chk * 16 + half * 8;
    qf[chk] = *(const frag8*)qp;
  }

  f32x16 o_[4];
  #pragma unroll
  for (int cm = 0; cm < 4; cm++)
    #pragma unroll
    for (int i = 0; i < 16; i++) o_[cm][i] = 0.f;
  float la0 = 0.f, la1 = 0.f;

  auto stage = [&](int k0, ushort* Kb, ushort* Vb) {
    #pragma unroll
    for (int it = 0; it < 2; it++) { // K tile 64x64 (8KB)
      int j = it * 256 + tid;
      int row = j >> 3, sch = (j & 7) ^ (row & 7);
      const ushort* kg = qk + (size_t)(b * N_ + k0 + row) * 2048 + 1024 + h2 * 64 + sch * 8;
      async16(kg, (char*)Kb + it * 4096 + w * 1024);
    }
    #pragma unroll
    for (int it = 0; it < 4; it++) { // V^T tile 128x64 (16KB)
      int j = it * 256 + tid;
      int row = j >> 3, sch = (j & 7) ^ (row & 7);
      const ushort* vg = vt + (size_t)(h * 128 + row) * 4096 + b * N_ + k0 + sch * 8;
      async16(vg, (char*)Vb + it * 4096 + w * 1024);
    }
  };

  auto compute = [&](const ushort* Kb, const ushort* Vb) {
    #pragma unroll
    for (int kh = 0; kh < 2; kh++) {
      f32x16 st;
      #pragma unroll
      for (int i = 0; i < 16; i++) st[i] = EXP2_GUARD;
      const int r = kh * 32 + lane31;
      #pragma unroll
      for (int chk = 0; chk < 4; chk++) {
        frag8 a = *(const frag8*)((const char*)Kb + r * 128 +
                                  (((chk << 1) | half) ^ (r & 7)) * 16);
        st = __builtin_amdgcn_mfma_f32_32x32x16_bf16(a, qf[chk], st, 0, 0, 0);
      }
      unsigned pk[8];
      #pragma unroll
      for (int p = 0; p < 8; p++) {
        float e0 = fast_exp2(st[2 * p]);
        float e1 = fast_exp2(st[2 * p + 1]);
        la0 += e0;
        la1 += e1;
        pk[p] = pkbf(e0, e1);
      }
      #pragma unroll
      for (int c16 = 0; c16 < 2; c16++) {
        unsigned p0 = pk[c16 * 4 + 0], p1 = pk[c16 * 4 + 1];
        unsigned p2 = pk[c16 * 4 + 2], p3 = pk[c16 * 4 + 3];
        unsigned m1 = (unsigned)__shfl_xor((int)(half ? p0 : p2), 32);
        unsigned m2 = (unsigned)__shfl_xor((int)(half ? p1 : p3), 32);
        union { unsigned u[4]; frag8 f; } u;
        u.u[0] = half ? m1 : p0;
        u.u[1] = half ? m2 : p1;
        u.u[2] = half ? p2 : m1;
        u.u[3] = half ? p3 : m2;
        frag8 bfr = u.f;
        #pragma unroll
        for (int cm = 0; cm < 4; cm++) {
          int c = cm * 32 + lane31;
          int g = (kh * 4 + c16 * 2 + half) ^ (c & 7);
          frag8 a = *(const frag8*)((const char*)Vb + c * 128 + g * 16);
          o_[cm] = __builtin_amdgcn_mfma_f32_32x32x16_bf16(a, bfr, o_[cm], 0, 0, 0);
        }
      }
    }
  };

  const int kbeg = ks * 1024;
  stage(kbeg, Klds0, Vlds0); // tile 0
  #pragma unroll 1
  for (int kt2 = 0; kt2 < 8; kt2++) {
    const int k0 = kbeg + kt2 * 128;
    __syncthreads();                 // tile 2*kt2 loads landed; buf1 free
    stage(k0 + 64, Klds1, Vlds1);    // prefetch tile 2*kt2+1 (always in range)
    compute(Klds0, Vlds0);           // tile 2*kt2
    __syncthreads();                 // tile 2*kt2+1 loads landed; buf0 free
    if (kt2 < 7)
      stage(k0 + 128, Klds0, Vlds0); // prefetch tile 2*kt2+2
    compute(Klds1, Vlds1);           // tile 2*kt2+1
  }

  // l: lane's partial covers half the k-rows; partner holds the rest
  float l_acc = la0 + la1;
  float lt = l_acc + __shfl_xor(l_acc, 32);
  if (half == 0)
    lbuf[(size_t)ks * 65536 + (size_t)(b * 16 + h2) * N_ + i0 + lane31] = lt;

  ushort* obase = opart + (size_t)ks * 8388608; // per-split half (2*MN bf16)
  {
    int q = i0 + lane31;
    ushort* ob = obase + ((size_t)((b * 16 + h2) * N_ + q)) * 128;
    #pragma unroll
    for (int cm = 0; cm < 4; cm++)
      #pragma unroll
      for (int g = 0; g < 4; g++) {
        int c = cm * 32 + g * 8 + half * 4;
        uint2 pv;
        pv.x = pkbf(o_[cm][4 * g + 0], o_[cm][4 * g + 1]);
        pv.y = pkbf(o_[cm][4 * g + 2], o_[cm][4 * g + 3]);
        *(uint2*)(ob + c) = pv;
      }
  }
}

// ---------------- combine (split-K sum + diff) + per-head LayerNorm -> bf16 ----------------
__global__ __launch_bounds__(256) void combine_ln_kernel(
    const ushort* __restrict__ opart, const float* __restrict__ lbuf,
    const float* __restrict__ lam_p,
    const float* __restrict__ ln_g, const float* __restrict__ ln_b,
    ushort* __restrict__ onorm) {
  const float lam = lam_p[0];
  const int wave = threadIdx.x >> 6, lane = threadIdx.x & 63;
  const int row = blockIdx.x * 4 + wave; // 0 .. B*H*N-1
  const int n = row & (N_ - 1);
  const int bh = row >> 11;
  const int h = bh & (H_ - 1);
  const int b = bh >> 3;

  const size_t re = (size_t)(b * 16 + 2 * h) * N_ + n;     // even half-head row
  const size_t ro = (size_t)(b * 16 + 2 * h + 1) * N_ + n; // odd half-head row
  const float rle = 1.0f / (lbuf[re] + lbuf[65536 + re]);
  const float rlo = 1.0f / (lbuf[ro] + lbuf[65536 + ro]);

  const int c = lane * 2;
  unsigned e0 = *(const unsigned*)(opart + re * 128 + c);
  unsigned e1 = *(const unsigned*)(opart + 8388608 + re * 128 + c);
  unsigned q0 = *(const unsigned*)(opart + ro * 128 + c);
  unsigned q1 = *(const unsigned*)(opart + 8388608 + ro * 128 + c);
  float ve0 = (bf2f_lo(e0) + bf2f_lo(e1)) * rle;
  float ve1 = (bf2f_hi(e0) + bf2f_hi(e1)) * rle;
  float vo0 = (bf2f_lo(q0) + bf2f_lo(q1)) * rlo;
  float vo1 = (bf2f_hi(q0) + bf2f_hi(q1)) * rlo;
  float v0 = ve0 - lam * vo0;
  float v1 = ve1 - lam * vo1;
  float sum = v0 + v1, ss = v0 * v0 + v1 * v1;
  #pragma unroll
  for (int off = 1; off < 64; off <<= 1) {
    sum += __shfl_xor(sum, off);
    ss += __shfl_xor(ss, off);
  }
  float mu = sum * (1.0f / 128.0f);
  float var = ss * (1.0f / 128.0f) - mu * mu;
  float r = rsqrtf(var + 1e-5f);
  float o0 = (v0 - mu) * r * ln_g[c] + ln_b[c];
  float o1 = (v1 - mu) * r * ln_g[c + 1] + ln_b[c + 1];
  unsigned pkv = (unsigned)f2bf(o0) | ((unsigned)f2bf(o1) << 16);
  *(unsigned*)(onorm + ((size_t)(b * N_ + n)) * E_ + h * 128 + c) = pkv;
}

// ---------------- launch ----------------
extern "C" void kernel_launch(void* const* d_in, const int* in_sizes, int n_in,
                              void* d_out, int out_size, void* d_ws, size_t ws_size,
                              hipStream_t stream) {
  const float* x    = (const float*)d_in[0];
  const float* Wq   = (const float*)d_in[1];
  const float* Wk   = (const float*)d_in[2];
  const float* Wv   = (const float*)d_in[3];
  const float* Wo   = (const float*)d_in[4];
  const float* lq1  = (const float*)d_in[5];
  const float* lk1  = (const float*)d_in[6];
  const float* lq2  = (const float*)d_in[7];
  const float* lk2  = (const float*)d_in[8];
  const float* ln_g = (const float*)d_in[9];
  const float* ln_b = (const float*)d_in[10];
  float* out = (float*)d_out;

  const size_t MN = (size_t)B_ * N_ * E_; // 4194304
  ushort* xb    = (ushort*)d_ws;          // bf16 x              (8 MB)
  ushort* wqkvt = xb + MN;                // bf16 [Wq;Wk;Wv]^T   (6 MB)
  ushort* wot   = wqkvt + 3 * 1048576;    // bf16 Wo^T           (2 MB)
  ushort* qkb   = wot + 1048576;          // bf16 qk [4096][2048] (16 MB)
  ushort* vtb   = qkb + (size_t)4096 * 2048; // bf16 v^T [1024][4096] (8 MB)
  ushort* op    = vtb + MN;               // bf16 partial O x2 splits (32 MB)
  float*  lbuf  = (float*)(op + 4 * MN);  // l partials x2 (512 KB)
  float*  lam   = lbuf + 2 * 65536;
  ushort* onorm = xb;                     // reuse x buffer after the projection gemm

  prep_kernel<<<dim3(3073), 256, 0, stream>>>(x, Wq, Wk, Wv, Wo, lq1, lk1, lq2, lk2,
                                              xb, wqkvt, wot, lam);

  // fused QK + V^T projection in ONE launch (768 blocks = 3 blocks/CU)
  gemm_qkv<<<dim3(768), 256, 0, stream>>>(xb, wqkvt, qkb, vtb, 0.125f * LOG2E);

  flash_kernel<<<dim3(N_ / 128, 16, B_ * 2), 256, 0, stream>>>(qkb, vtb, op, lbuf);
  combine_ln_kernel<<<dim3(B_ * H_ * N_ / 4), 256, 0, stream>>>(op, lbuf, lam, ln_g, ln_b, onorm);
  gemm_out<<<dim3(8, 64), 256, 0, stream>>>(onorm, wot, out);
}